// Round 19
// baseline (603.613 us; speedup 1.0000x reference)
//
#include <hip/hip_runtime.h>
#include <math.h>

#define NSIZE 20
#define NC 2000
#define H 128
#define NLAYER 3
#define EPB 380
#define NGRP 20

typedef float f32x4 __attribute__((ext_vector_type(4)));
typedef unsigned int u32x4 __attribute__((ext_vector_type(4)));
typedef unsigned short us8 __attribute__((ext_vector_type(8)));
typedef __bf16 bf16x8 __attribute__((ext_vector_type(8)));
typedef unsigned long long u64;

// packed-weight offsets in u32x4 (16B) units
#define OW_E 0
#define OW_K 2048
#define OW_Q 4096
#define OW_V 6144
#define OW_S 8192
#define OW_1 10240
#define OW_2 18432
#define OW_LAYER 26624
#define EA_OFF_B 2097152
// fragment-major edge copy: per clone, main [20g][4kt][64l][16B] = 81,920B
// + residue [5b4][4kt][64l][16B] = 20,480B  -> 102,400B/clone
#define FM_MAIN_B 81920
#define FM_CLONE_B 102400
#define WS_NEED (EA_OFF_B + (size_t)NC*FM_CLONE_B)

// LDS layout (bytes) — R18-proven (best 537us total).
// R19: manual ping-pong prefetch in phase-B main (named efA/efB force the
// allocator to keep g+1's loads in flight; pragma unroll provably doesn't -
// R16). VGPR budget: 64 now, cap 128 under lb(256,4); +32 for two buffers.
#define L_HBF   0        // [32][136] u16   8704
#define L_X2    8704     // [32][264] u16  16896 (aliases qarr/varr)
#define L_QARR  8704     // [20][140] u16   5600
#define L_VARR  14304    // [20][140] u16   5600
#define L_BM    25600    // [20][132] f32  10560
#define L_TOT   36160

static __device__ __forceinline__ unsigned short f2bf(float f){
  unsigned u = __float_as_uint(f);
  u += 0x7fffu + ((u >> 16) & 1u);          // RNE
  return (unsigned short)(u >> 16);
}
static __device__ __forceinline__ float bf2f(unsigned short b){
  return __uint_as_float(((unsigned)b) << 16);
}
static __device__ __forceinline__ unsigned pkbf(float a, float b){
  return (unsigned)f2bf(a) | ((unsigned)f2bf(b) << 16);
}
static __device__ __forceinline__ f32x4 MFMA(u32x4 a, u32x4 b, f32x4 c){
  return __builtin_amdgcn_mfma_f32_16x16x32_bf16(
      __builtin_bit_cast(bf16x8, a), __builtin_bit_cast(bf16x8, b), c, 0, 0, 0);
}
static __device__ __forceinline__ float sigm(float x){
  return __builtin_amdgcn_rcpf(1.f + __expf(-x));
}

// Pack W[K][N] f32 -> bf16 fragments (unchanged, proven).
__global__ __launch_bounds__(256) void pack_weights(
    const float* __restrict__ Wk, const float* __restrict__ Wq,
    const float* __restrict__ Wv, const float* __restrict__ We,
    const float* __restrict__ Ws, const float* __restrict__ W1,
    const float* __restrict__ W2, u32x4* __restrict__ outp)
{
  int l = blockIdx.x / 7, m = blockIdx.x % 7;
  const float* src; int K, N; long base;
  switch(m){
    case 0: src = We + (long)l*H*H;   K=H;   N=H;   base=OW_E; break;
    case 1: src = Wk + (long)l*H*H;   K=H;   N=H;   base=OW_K; break;
    case 2: src = Wq + (long)l*H*H;   K=H;   N=H;   base=OW_Q; break;
    case 3: src = Wv + (long)l*H*H;   K=H;   N=H;   base=OW_V; break;
    case 4: src = Ws + (long)l*H*H;   K=H;   N=H;   base=OW_S; break;
    case 5: src = W1 + (long)l*H*4*H; K=H;   N=4*H; base=OW_1; break;
    default: src = W2 + (long)l*4*H*H; K=4*H; N=H;  base=OW_2; break;
  }
  base += (long)l * OW_LAYER;
  int KT = K/32, NT = N/16;
  int total = KT*NT*64;
  for(int i = threadIdx.x; i < total; i += 256){
    int lane = i & 63, f = i >> 6;
    int kt = f % KT, nt = f / KT;
    int col = nt*16 + (lane & 15);
    int k0 = kt*32 + (lane >> 4)*8;
    us8 v;
    #pragma unroll
    for(int j=0;j<8;++j) v[j] = f2bf(src[(long)(k0+j)*N + col]);
    outp[base + (long)f*64 + lane] = __builtin_bit_cast(u32x4, v);
  }
}

// One block = one clone. Swapped GEMMs; node dim in l15.
// EAB: FM edge copy (R18) + manual ping-pong prefetch in phase B (R19).
template<bool EAB>
__global__ __launch_bounds__(256, 4) void moe_gnn(
    const float* __restrict__ x, const float* __restrict__ ea,
    unsigned short* __restrict__ eab,
    const float* __restrict__ g1, const float* __restrict__ b1,
    const float* __restrict__ g2, const float* __restrict__ b2,
    const u32x4* __restrict__ wp, float* __restrict__ out)
{
  __shared__ __align__(16) unsigned char smem[L_TOT];
  unsigned short* hbf  = (unsigned short*)(smem + L_HBF);   // [32][136]
  unsigned short* x2   = (unsigned short*)(smem + L_X2);    // [32][264]
  unsigned short* qarr = (unsigned short*)(smem + L_QARR);  // [20][140]
  unsigned short* varr = (unsigned short*)(smem + L_VARR);  // [20][140]
  float*          Bm   = (float*)(smem + L_BM);             // [20][132]

  const int c   = blockIdx.x;
  const int tid = threadIdx.x;
  const int w   = tid >> 6;
  const int l   = tid & 63;
  const int lg  = l >> 4;
  const int l15 = l & 15;
  const long cEPB = (long)c * EPB;
  const u32x4* fm = (const u32x4*)((const char*)eab + (long)c*FM_CLONE_B);

  if(EAB){
    // write fragment-major copy (linear/coalesced writes; reads 128B row
    // chunks with 8KB working set -> L1-resident; LESSON R4 honored).
    u32x4* fmw = (u32x4*)fm;
    const int WMAIN = NGRP*4*64;          // 5120
    const int WTOT  = WMAIN + 5*4*64;     // 6400
    for(int widx = tid; widx < WTOT; widx += 256){
      int g, s, kt, lidx;
      if(widx < WMAIN){
        g = widx >> 8; kt = (widx >> 6) & 3; lidx = widx & 63;
        int d = lidx & 15;
        s = (d == g) ? 0 : (d - (d > g ? 1 : 0));
      } else {
        int wr = widx - WMAIN;
        int b4 = wr >> 8; kt = (wr >> 6) & 3; lidx = wr & 63;
        int qi = (lidx & 15) >> 2, di = lidx & 3;
        g = b4*4 + qi; int d = 16 + di;
        s = (d == g) ? 0 : (d - (d > g ? 1 : 0));
      }
      int lgx = lidx >> 4;
      const float* sp = ea + (cEPB + (long)g*19 + s)*H + kt*32 + lgx*8;
      f32x4 a = *(const f32x4*)sp;
      f32x4 b = *(const f32x4*)(sp + 4);
      fmw[widx] = (u32x4){ pkbf(a[0],a[1]), pkbf(a[2],a[3]),
                           pkbf(b[0],b[1]), pkbf(b[2],b[3]) };
    }
  }
  for(int i = tid; i < 32*H; i += 256){
    int r = i >> 7, cc = i & 127;
    float v = (r < NSIZE) ? x[((long)c*NSIZE + r)*H + cc] : 0.f;
    hbf[r*136 + cc] = f2bf(v);
  }
  __syncthreads();

  #pragma unroll 1
  for(int layer = 0; layer < NLAYER; ++layer){
    const u32x4* wl = wp + (long)layer*OW_LAYER;
    f32x4 kreg[2][2];                 // k^T in-lane
    f32x4 agg[2][2];                  // skip + sum(msg), in-lane

    // ---- Phase A: swapped node GEMMs; k->regs, skip->agg, q/v->LDS ----
    {
      u32x4 hb[2][4];
      #pragma unroll
      for(int nt=0; nt<2; ++nt)
        #pragma unroll
        for(int kt=0; kt<4; ++kt)
          hb[nt][kt] = *(const u32x4*)&hbf[(nt*16+l15)*136 + kt*32 + lg*8];

      #pragma unroll
      for(int m=0; m<4; ++m){
        const long ow = (m==0?OW_K: m==1?OW_Q: m==2?OW_V: OW_S);
        #pragma unroll
        for(int mt=0; mt<2; ++mt)
          #pragma unroll
          for(int nt=0; nt<2; ++nt){
            f32x4 acc = {0.f,0.f,0.f,0.f};
            #pragma unroll
            for(int kt=0; kt<4; ++kt)
              acc = MFMA(wl[ow + (((2*w+mt)*4)+kt)*64 + l], hb[nt][kt], acc);
            if(m==0) kreg[mt][nt] = acc;
            else if(m==3) agg[mt][nt] = acc;
            else {
              unsigned short* dst = (m==1) ? qarr : varr;
              if(nt==0 || l15 < 4){
                u64 pk = (u64)pkbf(acc[0],acc[1]) | ((u64)pkbf(acc[2],acc[3]) << 32);
                *(u64*)&dst[(nt*16+l15)*140 + (2*w+mt)*16 + lg*4] = pk;
              }
            }
          }
      }
    }
    // no barrier: each wave reads back only its own q/v columns

    // ---- Phase B ----
    {
      u32x4 eB[2][4];
      #pragma unroll
      for(int mt=0;mt<2;++mt)
        #pragma unroll
        for(int kt=0;kt<4;++kt)
          eB[mt][kt] = wl[OW_E + ((2*w+mt)*4+kt)*64 + l];

      // gate+accumulate for one group's fragments
      auto GATE = [&](int g, const u32x4* ef){
        bool va = (l15 != g);
        #pragma unroll
        for(int mt=0; mt<2; ++mt){
          u64 q8 = *(const u64*)&qarr[g*140 + (2*w+mt)*16 + lg*4];
          u64 v8 = *(const u64*)&varr[g*140 + (2*w+mt)*16 + lg*4];
          f32x4 acc = {0.f,0.f,0.f,0.f};
          #pragma unroll
          for(int kt=0;kt<4;++kt)
            acc = MFMA(eB[mt][kt], ef[kt], acc);
          #pragma unroll
          for(int j=0;j<4;++j){
            float q_ = bf2f((unsigned short)(q8 >> (16*j)));
            float v_ = bf2f((unsigned short)(v8 >> (16*j)));
            float xg = acc[j] + kreg[mt][0][j] + q_;
            float m_ = sigm(xg) * v_;
            agg[mt][0][j] += va ? m_ : 0.f;
          }
        }
      };

      if(EAB){
        // manual ping-pong: load g+1 (other buffer) before computing g
        u32x4 efA[4], efB[4];
        #pragma unroll
        for(int kt=0;kt<4;++kt) efA[kt] = fm[kt*64 + l];            // g=0
        #pragma unroll 1
        for(int g=0; g<NGRP; g+=2){
          #pragma unroll
          for(int kt=0;kt<4;++kt) efB[kt] = fm[(g+1)*256 + kt*64 + l];
          GATE(g, efA);
          if(g+2 < NGRP){
            #pragma unroll
            for(int kt=0;kt<4;++kt) efA[kt] = fm[(g+2)*256 + kt*64 + l];
          }
          GATE(g+1, efB);
        }
      } else {
        #pragma unroll 2
        for(int g=0; g<NGRP; ++g){
          bool va = (l15 != g);
          int s = l15 - ((l15 > g) ? 1 : 0);
          long row = cEPB + (long)g*19 + (va ? s : 0);
          const float* ap = ea + row*H + lg*8;
          u32x4 ef[4];
          #pragma unroll
          for(int kt=0;kt<4;++kt){
            f32x4 lo = *(const f32x4*)(ap + kt*32);
            f32x4 hi = *(const f32x4*)(ap + kt*32 + 4);
            ef[kt] = (u32x4){ pkbf(lo[0],lo[1]), pkbf(lo[2],lo[3]),
                              pkbf(hi[0],hi[1]), pkbf(hi[2],hi[3]) };
          }
          GATE(g, ef);
        }
      }

      // residue pass: lane l15 = qi*4+di handles (g=qb+qi, d=16+di)
      {
        const int qi = l15 >> 2, di = l15 & 3;
        f32x4 aggR[2];
        aggR[0] = (f32x4){0.f,0.f,0.f,0.f};
        aggR[1] = (f32x4){0.f,0.f,0.f,0.f};
        const u32x4* rfm = fm + FM_MAIN_B/16;

        auto GATER = [&](int b4, const u32x4* ef){
          int g = b4*4 + qi;
          int d = 16 + di;
          bool va = (d != g);
          #pragma unroll
          for(int mt=0; mt<2; ++mt){
            u64 q8 = *(const u64*)&qarr[g*140 + (2*w+mt)*16 + lg*4];
            u64 v8 = *(const u64*)&varr[g*140 + (2*w+mt)*16 + lg*4];
            f32x4 acc = {0.f,0.f,0.f,0.f};
            #pragma unroll
            for(int kt=0;kt<4;++kt)
              acc = MFMA(eB[mt][kt], ef[kt], acc);
            #pragma unroll
            for(int j=0;j<4;++j){
              float kk = __shfl(kreg[mt][1][j], (lg<<4) | di, 64);
              float q_ = bf2f((unsigned short)(q8 >> (16*j)));
              float v_ = bf2f((unsigned short)(v8 >> (16*j)));
              float xg = acc[j] + kk + q_;
              float m_ = sigm(xg) * v_;
              aggR[mt][j] += va ? m_ : 0.f;
            }
          }
        };

        if(EAB){
          u32x4 efR[4], efN[4];
          #pragma unroll
          for(int kt=0;kt<4;++kt) efR[kt] = rfm[kt*64 + l];         // b4=0
          #pragma unroll 1
          for(int b4=0; b4<5; ++b4){
            if(b4+1 < 5){
              #pragma unroll
              for(int kt=0;kt<4;++kt) efN[kt] = rfm[(b4+1)*256 + kt*64 + l];
            }
            GATER(b4, efR);
            #pragma unroll
            for(int kt=0;kt<4;++kt) efR[kt] = efN[kt];
          }
        } else {
          #pragma unroll 1
          for(int b4=0; b4<5; ++b4){
            int g = b4*4 + qi;
            int d = 16 + di;
            bool va = (d != g);
            int s = d - ((d > g) ? 1 : 0);
            long row = cEPB + (long)g*19 + (va ? s : 0);
            const float* ap = ea + row*H + lg*8;
            u32x4 ef[4];
            #pragma unroll
            for(int kt=0;kt<4;++kt){
              f32x4 lo = *(const f32x4*)(ap + kt*32);
              f32x4 hi = *(const f32x4*)(ap + kt*32 + 4);
              ef[kt] = (u32x4){ pkbf(lo[0],lo[1]), pkbf(lo[2],lo[3]),
                                pkbf(hi[0],hi[1]), pkbf(hi[2],hi[3]) };
            }
            GATER(b4, ef);
          }
        }
        #pragma unroll
        for(int mt=0; mt<2; ++mt)
          #pragma unroll
          for(int j=0;j<4;++j){
            float t = aggR[mt][j];
            t += __shfl_xor(t, 4, 64);
            t += __shfl_xor(t, 8, 64);
            agg[mt][1][j] += t;
          }
      }

      // Bm[d][col] = skip + agg (single b128 store, own cols)
      #pragma unroll
      for(int nt=0; nt<2; ++nt)
        if(nt==0 || l15 < 4)
          #pragma unroll
          for(int mt=0; mt<2; ++mt)
            *(f32x4*)&Bm[(nt*16+l15)*132 + (2*w+mt)*16 + lg*4] = agg[mt][nt];
    }
    __syncthreads();

    // ---- Phase C: LN1 -> Bm (f32) + hbf (bf16) ----
    {
      const float* gp = g1 + layer*H; const float* bp = b1 + layer*H;
      float gv0 = gp[l], gv1 = gp[64+l], bv0 = bp[l], bv1 = bp[64+l];
      for(int i=0;i<5;++i){
        int r = w + 4*i;
        float v0 = Bm[r*132 + l], v1 = Bm[r*132 + 64 + l];
        float s = v0+v1;
        #pragma unroll
        for(int m=1;m<64;m<<=1) s += __shfl_xor(s, m, 64);
        float mu = s*(1.f/128.f);
        float d0=v0-mu, d1=v1-mu;
        float qv = d0*d0 + d1*d1;
        #pragma unroll
        for(int m=1;m<64;m<<=1) qv += __shfl_xor(qv, m, 64);
        float rs = rsqrtf(qv*(1.f/128.f) + 1e-5f);
        float y0 = d0*rs*gv0 + bv0;
        float y1 = d1*rs*gv1 + bv1;
        Bm[r*132 + l] = y0; Bm[r*132 + 64 + l] = y1;
        hbf[r*136 + l] = f2bf(y0); hbf[r*136 + 64 + l] = f2bf(y1);
      }
    }
    __syncthreads();

    // ---- Phase D: FFN (two 256-col halves; x2 aliases qarr/varr) ----
    {
      u32x4 hb2[2][4];
      #pragma unroll
      for(int nt=0;nt<2;++nt)
        #pragma unroll
        for(int kt=0;kt<4;++kt)
          hb2[nt][kt] = *(const u32x4*)&hbf[(nt*16+l15)*136 + kt*32 + lg*8];
      f32x4 c2[2][2];
      #pragma unroll
      for(int mt=0;mt<2;++mt)
        #pragma unroll
        for(int nt=0;nt<2;++nt)
          c2[mt][nt] = (f32x4){0.f,0.f,0.f,0.f};
      #pragma unroll 1
      for(int hh=0; hh<2; ++hh){
        for(int i2=0;i2<4;++i2){
          int mtg = hh*16 + w*4 + i2;
          #pragma unroll
          for(int nt=0;nt<2;++nt){
            f32x4 acc = {0.f,0.f,0.f,0.f};
            #pragma unroll
            for(int kt=0;kt<4;++kt)
              acc = MFMA(wl[OW_1 + (mtg*4+kt)*64 + l], hb2[nt][kt], acc);
            float ge[4];
            #pragma unroll
            for(int j=0;j<4;++j){
              float v = acc[j];
              float u = v*(0.7978845608f + 0.0356774081f*v*v);
              ge[j] = v * sigm(2.f*u);
            }
            u64 pk = (u64)pkbf(ge[0],ge[1]) | ((u64)pkbf(ge[2],ge[3]) << 32);
            *(u64*)&x2[(nt*16+l15)*264 + (w*4+i2)*16 + lg*4] = pk;
          }
        }
        __syncthreads();
        #pragma unroll
        for(int nt=0;nt<2;++nt){
          #pragma unroll
          for(int kt=0;kt<8;++kt){
            u32x4 xb = *(const u32x4*)&x2[(nt*16+l15)*264 + kt*32 + lg*8];
            #pragma unroll
            for(int mt=0;mt<2;++mt)
              c2[mt][nt] = MFMA(wl[OW_2 + ((2*w+mt)*16 + hh*8 + kt)*64 + l],
                                xb, c2[mt][nt]);
          }
        }
        __syncthreads();
      }
      #pragma unroll
      for(int nt=0;nt<2;++nt)
        if(nt==0 || l15 < 4)
          #pragma unroll
          for(int mt=0;mt<2;++mt){
            float* p = &Bm[(nt*16+l15)*132 + (2*w+mt)*16 + lg*4];
            *(f32x4*)p = *(f32x4*)p + c2[mt][nt];
          }
    }
    __syncthreads();

    // ---- Phase E: LN2 -> hbf (next layer); final layer -> d_out (NT) ----
    {
      const float* gp = g2 + layer*H; const float* bp = b2 + layer*H;
      float gv0 = gp[l], gv1 = gp[64+l], bv0 = bp[l], bv1 = bp[64+l];
      for(int i=0;i<5;++i){
        int r = w + 4*i;
        float v0 = Bm[r*132 + l], v1 = Bm[r*132 + 64 + l];
        float s = v0+v1;
        #pragma unroll
        for(int m=1;m<64;m<<=1) s += __shfl_xor(s, m, 64);
        float mu = s*(1.f/128.f);
        float d0=v0-mu, d1=v1-mu;
        float qv = d0*d0 + d1*d1;
        #pragma unroll
        for(int m=1;m<64;m<<=1) qv += __shfl_xor(qv, m, 64);
        float rs = rsqrtf(qv*(1.f/128.f) + 1e-5f);
        float y0 = d0*rs*gv0 + bv0;
        float y1 = d1*rs*gv1 + bv1;
        hbf[r*136 + l] = f2bf(y0); hbf[r*136 + 64 + l] = f2bf(y1);
        if(layer == NLAYER-1){
          __builtin_nontemporal_store(y0, &out[((long)c*NSIZE + r)*H + l]);
          __builtin_nontemporal_store(y1, &out[((long)c*NSIZE + r)*H + 64 + l]);
        }
      }
    }
    __syncthreads();
  }
}

extern "C" void kernel_launch(void* const* d_in, const int* in_sizes, int n_in,
                              void* d_out, int out_size, void* d_ws, size_t ws_size,
                              hipStream_t stream) {
  const float* x  = (const float*)d_in[0];
  const float* ea = (const float*)d_in[1];
  const float* Wk = (const float*)d_in[2];
  const float* Wq = (const float*)d_in[3];
  const float* Wv = (const float*)d_in[4];
  const float* We = (const float*)d_in[5];
  const float* Ws = (const float*)d_in[6];
  const float* W1 = (const float*)d_in[7];
  const float* W2 = (const float*)d_in[8];
  const float* g1 = (const float*)d_in[9];
  const float* b1 = (const float*)d_in[10];
  const float* g2 = (const float*)d_in[11];
  const float* b2 = (const float*)d_in[12];
  u32x4* wp = (u32x4*)d_ws;

  hipLaunchKernelGGL(pack_weights, dim3(21), dim3(256), 0, stream,
                     Wk, Wq, Wv, We, Ws, W1, W2, wp);
  if(ws_size >= WS_NEED){
    unsigned short* eab = (unsigned short*)((char*)d_ws + EA_OFF_B);
    hipLaunchKernelGGL(moe_gnn<true>, dim3(NC), dim3(256), 0, stream,
                       x, ea, eab, g1, b1, g2, b2, wp, (float*)d_out);
  } else {
    hipLaunchKernelGGL(moe_gnn<false>, dim3(NC), dim3(256), 0, stream,
                       x, ea, (unsigned short*)nullptr,
                       g1, b1, g2, b2, wp, (float*)d_out);
  }
}

// Round 20
// 536.054 us; speedup vs baseline: 1.1260x; 1.1260x over previous
//
#include <hip/hip_runtime.h>
#include <math.h>

#define NSIZE 20
#define NC 2000
#define H 128
#define NLAYER 3
#define EPB 380
#define NGRP 20

typedef float f32x4 __attribute__((ext_vector_type(4)));
typedef unsigned int u32x4 __attribute__((ext_vector_type(4)));
typedef unsigned short us8 __attribute__((ext_vector_type(8)));
typedef __bf16 bf16x8 __attribute__((ext_vector_type(8)));
typedef unsigned long long u64;

// packed-weight offsets in u32x4 (16B) units
#define OW_E 0
#define OW_K 2048
#define OW_Q 4096
#define OW_V 6144
#define OW_S 8192
#define OW_1 10240
#define OW_2 18432
#define OW_LAYER 26624
#define EA_OFF_B 2097152
// fragment-major edge copy: per clone, main [20g][4kt][64l][16B] = 81,920B
// + residue [5b4][4kt][64l][16B] = 20,480B  -> 102,400B/clone
#define FM_MAIN_B 81920
#define FM_CLONE_B 102400
#define WS_NEED (EA_OFF_B + (size_t)NC*FM_CLONE_B)

// LDS layout (bytes) — R18 optimum (537us total), reverted after R19's
// ping-pong spill regression (WRITE +146MB scratch signature at pinned
// 64 VGPR). LESSONS: occupancy pinned ~45% (R13/R14); traffic floor
// ~1.27GB (R15); pipeline depth compiler-capped (R16/R19); staging
// barrier-bound (R17). FM layout + plain coalesced reads is the optimum.
#define L_HBF   0        // [32][136] u16   8704
#define L_X2    8704     // [32][264] u16  16896 (aliases qarr/varr)
#define L_QARR  8704     // [20][140] u16   5600
#define L_VARR  14304    // [20][140] u16   5600
#define L_BM    25600    // [20][132] f32  10560
#define L_TOT   36160

static __device__ __forceinline__ unsigned short f2bf(float f){
  unsigned u = __float_as_uint(f);
  u += 0x7fffu + ((u >> 16) & 1u);          // RNE
  return (unsigned short)(u >> 16);
}
static __device__ __forceinline__ float bf2f(unsigned short b){
  return __uint_as_float(((unsigned)b) << 16);
}
static __device__ __forceinline__ unsigned pkbf(float a, float b){
  return (unsigned)f2bf(a) | ((unsigned)f2bf(b) << 16);
}
static __device__ __forceinline__ f32x4 MFMA(u32x4 a, u32x4 b, f32x4 c){
  return __builtin_amdgcn_mfma_f32_16x16x32_bf16(
      __builtin_bit_cast(bf16x8, a), __builtin_bit_cast(bf16x8, b), c, 0, 0, 0);
}
static __device__ __forceinline__ float sigm(float x){
  return __builtin_amdgcn_rcpf(1.f + __expf(-x));
}

// Pack W[K][N] f32 -> bf16 fragments (unchanged, proven).
__global__ __launch_bounds__(256) void pack_weights(
    const float* __restrict__ Wk, const float* __restrict__ Wq,
    const float* __restrict__ Wv, const float* __restrict__ We,
    const float* __restrict__ Ws, const float* __restrict__ W1,
    const float* __restrict__ W2, u32x4* __restrict__ outp)
{
  int l = blockIdx.x / 7, m = blockIdx.x % 7;
  const float* src; int K, N; long base;
  switch(m){
    case 0: src = We + (long)l*H*H;   K=H;   N=H;   base=OW_E; break;
    case 1: src = Wk + (long)l*H*H;   K=H;   N=H;   base=OW_K; break;
    case 2: src = Wq + (long)l*H*H;   K=H;   N=H;   base=OW_Q; break;
    case 3: src = Wv + (long)l*H*H;   K=H;   N=H;   base=OW_V; break;
    case 4: src = Ws + (long)l*H*H;   K=H;   N=H;   base=OW_S; break;
    case 5: src = W1 + (long)l*H*4*H; K=H;   N=4*H; base=OW_1; break;
    default: src = W2 + (long)l*4*H*H; K=4*H; N=H;  base=OW_2; break;
  }
  base += (long)l * OW_LAYER;
  int KT = K/32, NT = N/16;
  int total = KT*NT*64;
  for(int i = threadIdx.x; i < total; i += 256){
    int lane = i & 63, f = i >> 6;
    int kt = f % KT, nt = f / KT;
    int col = nt*16 + (lane & 15);
    int k0 = kt*32 + (lane >> 4)*8;
    us8 v;
    #pragma unroll
    for(int j=0;j<8;++j) v[j] = f2bf(src[(long)(k0+j)*N + col]);
    outp[base + (long)f*64 + lane] = __builtin_bit_cast(u32x4, v);
  }
}

// One block = one clone. Swapped GEMMs; node dim in l15.
// EAB: prologue writes a fragment-major bf16 edge copy (linear writes,
// L1-cached permuted reads); phase B reads it with plain coalesced per-lane
// loads — zero address math, no staging barriers.
template<bool EAB>
__global__ __launch_bounds__(256, 4) void moe_gnn(
    const float* __restrict__ x, const float* __restrict__ ea,
    unsigned short* __restrict__ eab,
    const float* __restrict__ g1, const float* __restrict__ b1,
    const float* __restrict__ g2, const float* __restrict__ b2,
    const u32x4* __restrict__ wp, float* __restrict__ out)
{
  __shared__ __align__(16) unsigned char smem[L_TOT];
  unsigned short* hbf  = (unsigned short*)(smem + L_HBF);   // [32][136]
  unsigned short* x2   = (unsigned short*)(smem + L_X2);    // [32][264]
  unsigned short* qarr = (unsigned short*)(smem + L_QARR);  // [20][140]
  unsigned short* varr = (unsigned short*)(smem + L_VARR);  // [20][140]
  float*          Bm   = (float*)(smem + L_BM);             // [20][132]

  const int c   = blockIdx.x;
  const int tid = threadIdx.x;
  const int w   = tid >> 6;
  const int l   = tid & 63;
  const int lg  = l >> 4;
  const int l15 = l & 15;
  const long cEPB = (long)c * EPB;
  const u32x4* fm = (const u32x4*)((const char*)eab + (long)c*FM_CLONE_B);

  if(EAB){
    // write fragment-major copy: word widx=(g,kt,l) or residue (b4,kt,l).
    // Writes linear/coalesced; reads are 128B-contiguous row chunks with an
    // 8KB/16-row working set -> L1-resident (LESSON R4 honored).
    u32x4* fmw = (u32x4*)fm;
    const int WMAIN = NGRP*4*64;          // 5120
    const int WTOT  = WMAIN + 5*4*64;     // 6400
    for(int widx = tid; widx < WTOT; widx += 256){
      int g, s, kt, lidx;
      if(widx < WMAIN){
        g = widx >> 8; kt = (widx >> 6) & 3; lidx = widx & 63;
        int d = lidx & 15;
        s = (d == g) ? 0 : (d - (d > g ? 1 : 0));
      } else {
        int wr = widx - WMAIN;
        int b4 = wr >> 8; kt = (wr >> 6) & 3; lidx = wr & 63;
        int qi = (lidx & 15) >> 2, di = lidx & 3;
        g = b4*4 + qi; int d = 16 + di;
        s = (d == g) ? 0 : (d - (d > g ? 1 : 0));
      }
      int lgx = lidx >> 4;
      const float* sp = ea + (cEPB + (long)g*19 + s)*H + kt*32 + lgx*8;
      f32x4 a = *(const f32x4*)sp;
      f32x4 b = *(const f32x4*)(sp + 4);
      fmw[widx] = (u32x4){ pkbf(a[0],a[1]), pkbf(a[2],a[3]),
                           pkbf(b[0],b[1]), pkbf(b[2],b[3]) };
    }
  }
  for(int i = tid; i < 32*H; i += 256){
    int r = i >> 7, cc = i & 127;
    float v = (r < NSIZE) ? x[((long)c*NSIZE + r)*H + cc] : 0.f;
    hbf[r*136 + cc] = f2bf(v);
  }
  __syncthreads();

  #pragma unroll 1
  for(int layer = 0; layer < NLAYER; ++layer){
    const u32x4* wl = wp + (long)layer*OW_LAYER;
    f32x4 kreg[2][2];                 // k^T in-lane
    f32x4 agg[2][2];                  // skip + sum(msg), in-lane

    // ---- Phase A: swapped node GEMMs; k->regs, skip->agg, q/v->LDS ----
    {
      u32x4 hb[2][4];
      #pragma unroll
      for(int nt=0; nt<2; ++nt)
        #pragma unroll
        for(int kt=0; kt<4; ++kt)
          hb[nt][kt] = *(const u32x4*)&hbf[(nt*16+l15)*136 + kt*32 + lg*8];

      #pragma unroll
      for(int m=0; m<4; ++m){
        const long ow = (m==0?OW_K: m==1?OW_Q: m==2?OW_V: OW_S);
        #pragma unroll
        for(int mt=0; mt<2; ++mt)
          #pragma unroll
          for(int nt=0; nt<2; ++nt){
            f32x4 acc = {0.f,0.f,0.f,0.f};
            #pragma unroll
            for(int kt=0; kt<4; ++kt)
              acc = MFMA(wl[ow + (((2*w+mt)*4)+kt)*64 + l], hb[nt][kt], acc);
            if(m==0) kreg[mt][nt] = acc;
            else if(m==3) agg[mt][nt] = acc;
            else {
              unsigned short* dst = (m==1) ? qarr : varr;
              if(nt==0 || l15 < 4){
                u64 pk = (u64)pkbf(acc[0],acc[1]) | ((u64)pkbf(acc[2],acc[3]) << 32);
                *(u64*)&dst[(nt*16+l15)*140 + (2*w+mt)*16 + lg*4] = pk;
              }
            }
          }
      }
    }
    // no barrier: each wave reads back only its own q/v columns

    // ---- Phase B ----
    {
      u32x4 eB[2][4];
      #pragma unroll
      for(int mt=0;mt<2;++mt)
        #pragma unroll
        for(int kt=0;kt<4;++kt)
          eB[mt][kt] = wl[OW_E + ((2*w+mt)*4+kt)*64 + l];

      // main pass: d = l15 in [0,16); FM reads = coalesced, no addr math
      #pragma unroll 2
      for(int g=0; g<NGRP; ++g){
        bool va = (l15 != g);
        u32x4 ef[4];
        if(EAB){
          #pragma unroll
          for(int kt=0;kt<4;++kt)
            ef[kt] = fm[g*256 + kt*64 + l];
        } else {
          int s = l15 - ((l15 > g) ? 1 : 0);
          long row = cEPB + (long)g*19 + (va ? s : 0);
          const float* ap = ea + row*H + lg*8;
          #pragma unroll
          for(int kt=0;kt<4;++kt){
            f32x4 lo = *(const f32x4*)(ap + kt*32);
            f32x4 hi = *(const f32x4*)(ap + kt*32 + 4);
            ef[kt] = (u32x4){ pkbf(lo[0],lo[1]), pkbf(lo[2],lo[3]),
                              pkbf(hi[0],hi[1]), pkbf(hi[2],hi[3]) };
          }
        }
        #pragma unroll
        for(int mt=0; mt<2; ++mt){
          u64 q8 = *(const u64*)&qarr[g*140 + (2*w+mt)*16 + lg*4];
          u64 v8 = *(const u64*)&varr[g*140 + (2*w+mt)*16 + lg*4];
          f32x4 acc = {0.f,0.f,0.f,0.f};
          #pragma unroll
          for(int kt=0;kt<4;++kt)
            acc = MFMA(eB[mt][kt], ef[kt], acc);
          #pragma unroll
          for(int j=0;j<4;++j){
            float q_ = bf2f((unsigned short)(q8 >> (16*j)));
            float v_ = bf2f((unsigned short)(v8 >> (16*j)));
            float xg = acc[j] + kreg[mt][0][j] + q_;
            float m_ = sigm(xg) * v_;
            agg[mt][0][j] += va ? m_ : 0.f;
          }
        }
      }

      // residue pass: lane l15 = qi*4+di handles (g=qb+qi, d=16+di)
      {
        const int qi = l15 >> 2, di = l15 & 3;
        f32x4 aggR[2];
        aggR[0] = (f32x4){0.f,0.f,0.f,0.f};
        aggR[1] = (f32x4){0.f,0.f,0.f,0.f};
        const u32x4* rfm = fm + FM_MAIN_B/16;
        #pragma unroll 1
        for(int b4=0; b4<5; ++b4){
          int g = b4*4 + qi;
          int d = 16 + di;
          bool va = (d != g);
          u32x4 ef[4];
          if(EAB){
            #pragma unroll
            for(int kt=0;kt<4;++kt)
              ef[kt] = rfm[b4*256 + kt*64 + l];
          } else {
            int s = d - ((d > g) ? 1 : 0);
            long row = cEPB + (long)g*19 + (va ? s : 0);
            const float* ap = ea + row*H + lg*8;
            #pragma unroll
            for(int kt=0;kt<4;++kt){
              f32x4 lo = *(const f32x4*)(ap + kt*32);
              f32x4 hi = *(const f32x4*)(ap + kt*32 + 4);
              ef[kt] = (u32x4){ pkbf(lo[0],lo[1]), pkbf(lo[2],lo[3]),
                                pkbf(hi[0],hi[1]), pkbf(hi[2],hi[3]) };
            }
          }
          #pragma unroll
          for(int mt=0; mt<2; ++mt){
            u64 q8 = *(const u64*)&qarr[g*140 + (2*w+mt)*16 + lg*4];
            u64 v8 = *(const u64*)&varr[g*140 + (2*w+mt)*16 + lg*4];
            f32x4 acc = {0.f,0.f,0.f,0.f};
            #pragma unroll
            for(int kt=0;kt<4;++kt)
              acc = MFMA(eB[mt][kt], ef[kt], acc);
            #pragma unroll
            for(int j=0;j<4;++j){
              float kk = __shfl(kreg[mt][1][j], (lg<<4) | di, 64);
              float q_ = bf2f((unsigned short)(q8 >> (16*j)));
              float v_ = bf2f((unsigned short)(v8 >> (16*j)));
              float xg = acc[j] + kk + q_;
              float m_ = sigm(xg) * v_;
              aggR[mt][j] += va ? m_ : 0.f;
            }
          }
        }
        #pragma unroll
        for(int mt=0; mt<2; ++mt)
          #pragma unroll
          for(int j=0;j<4;++j){
            float t = aggR[mt][j];
            t += __shfl_xor(t, 4, 64);
            t += __shfl_xor(t, 8, 64);
            agg[mt][1][j] += t;
          }
      }

      // Bm[d][col] = skip + agg (single b128 store, own cols)
      #pragma unroll
      for(int nt=0; nt<2; ++nt)
        if(nt==0 || l15 < 4)
          #pragma unroll
          for(int mt=0; mt<2; ++mt)
            *(f32x4*)&Bm[(nt*16+l15)*132 + (2*w+mt)*16 + lg*4] = agg[mt][nt];
    }
    __syncthreads();

    // ---- Phase C: LN1 -> Bm (f32) + hbf (bf16) ----
    {
      const float* gp = g1 + layer*H; const float* bp = b1 + layer*H;
      float gv0 = gp[l], gv1 = gp[64+l], bv0 = bp[l], bv1 = bp[64+l];
      for(int i=0;i<5;++i){
        int r = w + 4*i;
        float v0 = Bm[r*132 + l], v1 = Bm[r*132 + 64 + l];
        float s = v0+v1;
        #pragma unroll
        for(int m=1;m<64;m<<=1) s += __shfl_xor(s, m, 64);
        float mu = s*(1.f/128.f);
        float d0=v0-mu, d1=v1-mu;
        float qv = d0*d0 + d1*d1;
        #pragma unroll
        for(int m=1;m<64;m<<=1) qv += __shfl_xor(qv, m, 64);
        float rs = rsqrtf(qv*(1.f/128.f) + 1e-5f);
        float y0 = d0*rs*gv0 + bv0;
        float y1 = d1*rs*gv1 + bv1;
        Bm[r*132 + l] = y0; Bm[r*132 + 64 + l] = y1;
        hbf[r*136 + l] = f2bf(y0); hbf[r*136 + 64 + l] = f2bf(y1);
      }
    }
    __syncthreads();

    // ---- Phase D: FFN (two 256-col halves; x2 aliases qarr/varr) ----
    {
      u32x4 hb2[2][4];
      #pragma unroll
      for(int nt=0;nt<2;++nt)
        #pragma unroll
        for(int kt=0;kt<4;++kt)
          hb2[nt][kt] = *(const u32x4*)&hbf[(nt*16+l15)*136 + kt*32 + lg*8];
      f32x4 c2[2][2];
      #pragma unroll
      for(int mt=0;mt<2;++mt)
        #pragma unroll
        for(int nt=0;nt<2;++nt)
          c2[mt][nt] = (f32x4){0.f,0.f,0.f,0.f};
      #pragma unroll 1
      for(int hh=0; hh<2; ++hh){
        for(int i2=0;i2<4;++i2){
          int mtg = hh*16 + w*4 + i2;
          #pragma unroll
          for(int nt=0;nt<2;++nt){
            f32x4 acc = {0.f,0.f,0.f,0.f};
            #pragma unroll
            for(int kt=0;kt<4;++kt)
              acc = MFMA(wl[OW_1 + (mtg*4+kt)*64 + l], hb2[nt][kt], acc);
            float ge[4];
            #pragma unroll
            for(int j=0;j<4;++j){
              float v = acc[j];
              float u = v*(0.7978845608f + 0.0356774081f*v*v);
              ge[j] = v * sigm(2.f*u);
            }
            u64 pk = (u64)pkbf(ge[0],ge[1]) | ((u64)pkbf(ge[2],ge[3]) << 32);
            *(u64*)&x2[(nt*16+l15)*264 + (w*4+i2)*16 + lg*4] = pk;
          }
        }
        __syncthreads();
        #pragma unroll
        for(int nt=0;nt<2;++nt){
          #pragma unroll
          for(int kt=0;kt<8;++kt){
            u32x4 xb = *(const u32x4*)&x2[(nt*16+l15)*264 + kt*32 + lg*8];
            #pragma unroll
            for(int mt=0;mt<2;++mt)
              c2[mt][nt] = MFMA(wl[OW_2 + ((2*w+mt)*16 + hh*8 + kt)*64 + l],
                                xb, c2[mt][nt]);
          }
        }
        __syncthreads();
      }
      #pragma unroll
      for(int nt=0;nt<2;++nt)
        if(nt==0 || l15 < 4)
          #pragma unroll
          for(int mt=0;mt<2;++mt){
            float* p = &Bm[(nt*16+l15)*132 + (2*w+mt)*16 + lg*4];
            *(f32x4*)p = *(f32x4*)p + c2[mt][nt];
          }
    }
    __syncthreads();

    // ---- Phase E: LN2 -> hbf (next layer); final layer -> d_out (NT) ----
    {
      const float* gp = g2 + layer*H; const float* bp = b2 + layer*H;
      float gv0 = gp[l], gv1 = gp[64+l], bv0 = bp[l], bv1 = bp[64+l];
      for(int i=0;i<5;++i){
        int r = w + 4*i;
        float v0 = Bm[r*132 + l], v1 = Bm[r*132 + 64 + l];
        float s = v0+v1;
        #pragma unroll
        for(int m=1;m<64;m<<=1) s += __shfl_xor(s, m, 64);
        float mu = s*(1.f/128.f);
        float d0=v0-mu, d1=v1-mu;
        float qv = d0*d0 + d1*d1;
        #pragma unroll
        for(int m=1;m<64;m<<=1) qv += __shfl_xor(qv, m, 64);
        float rs = rsqrtf(qv*(1.f/128.f) + 1e-5f);
        float y0 = d0*rs*gv0 + bv0;
        float y1 = d1*rs*gv1 + bv1;
        hbf[r*136 + l] = f2bf(y0); hbf[r*136 + 64 + l] = f2bf(y1);
        if(layer == NLAYER-1){
          __builtin_nontemporal_store(y0, &out[((long)c*NSIZE + r)*H + l]);
          __builtin_nontemporal_store(y1, &out[((long)c*NSIZE + r)*H + 64 + l]);
        }
      }
    }
    __syncthreads();
  }
}

extern "C" void kernel_launch(void* const* d_in, const int* in_sizes, int n_in,
                              void* d_out, int out_size, void* d_ws, size_t ws_size,
                              hipStream_t stream) {
  const float* x  = (const float*)d_in[0];
  const float* ea = (const float*)d_in[1];
  const float* Wk = (const float*)d_in[2];
  const float* Wq = (const float*)d_in[3];
  const float* Wv = (const float*)d_in[4];
  const float* We = (const float*)d_in[5];
  const float* Ws = (const float*)d_in[6];
  const float* W1 = (const float*)d_in[7];
  const float* W2 = (const float*)d_in[8];
  const float* g1 = (const float*)d_in[9];
  const float* b1 = (const float*)d_in[10];
  const float* g2 = (const float*)d_in[11];
  const float* b2 = (const float*)d_in[12];
  u32x4* wp = (u32x4*)d_ws;

  hipLaunchKernelGGL(pack_weights, dim3(21), dim3(256), 0, stream,
                     Wk, Wq, Wv, We, Ws, W1, W2, wp);
  if(ws_size >= WS_NEED){
    unsigned short* eab = (unsigned short*)((char*)d_ws + EA_OFF_B);
    hipLaunchKernelGGL(moe_gnn<true>, dim3(NC), dim3(256), 0, stream,
                       x, ea, eab, g1, b1, g2, b2, wp, (float*)d_out);
  } else {
    hipLaunchKernelGGL(moe_gnn<false>, dim3(NC), dim3(256), 0, stream,
                       x, ea, (unsigned short*)nullptr,
                       g1, b1, g2, b2, wp, (float*)d_out);
  }
}